// Round 11
// baseline (347.581 us; speedup 1.0000x reference)
//
#include <hip/hip_runtime.h>
#include <hip/hip_fp16.h>

typedef __half h16;
static __device__ __forceinline__ h16  f2h(float v){ return __float2half(v); }

typedef _Float16 f16x8 __attribute__((ext_vector_type(8)));
typedef float    f32x4 __attribute__((ext_vector_type(4)));
// clang ext-vector types for nontemporal builtins (HIP_vector_type is rejected)
typedef float    f32x4v __attribute__((ext_vector_type(4)));
typedef float    f32x2v __attribute__((ext_vector_type(2)));

// pack two floats -> h2 in a uint (RNE)
static __device__ __forceinline__ unsigned pk2(float a, float b){
  return ((unsigned)__half_as_ushort(__float2half(b)) << 16) |
          (unsigned)__half_as_ushort(__float2half(a));
}

#define HEADS 8
#define HID 32
#define NHID 256

// ---------------- CSR build (deg zeroed via memset) ----------------
// R10: single atomic range-allocator instead of prefix-scan chain (CSR only needs
// CONTIGUOUS per-node ranges). One atomicAdd per WAVE via shfl_up wave-scan.
// count_deg stays merged with weight packing (independent block ranges).
__global__ void k_count_pack(const int* __restrict__ ei, int* __restrict__ deg, int E, int EB,
                             const float* __restrict__ W1, const float* __restrict__ W2,
                             const float* __restrict__ Wp1, const float* __restrict__ Wm1,
                             const float* __restrict__ Wm2,
                             _Float16* __restrict__ Wpk1, _Float16* __restrict__ Wpk2,
                             _Float16* __restrict__ Wpkp, _Float16* __restrict__ Apke){
  const int b = blockIdx.x;
  if (b < EB){
    int e = b*256 + threadIdx.x;
    if (e < E) atomicAdd(&deg[ei[E + e]], 1);   // dst = edge_index[1]
    return;
  }
  int idx = (b - EB)*256 + threadIdx.x;
  if (idx < 32768){
    int i = idx;
    int j=i&7, lane=(i>>3)&63, ct=(i>>9)&15, kc=i>>13;
    int k = kc*32 + ((lane>>4)<<3) + j, c = (ct<<4) + (lane&15);
    Wpk1[i] = (_Float16)W1[(size_t)k*NHID + c];
  } else if (idx < 98304){
    int i = idx - 32768;
    int j=i&7, lane=(i>>3)&63, ct=(i>>9)&15, kc=i>>13;
    int k = kc*32 + ((lane>>4)<<3) + j, c = (ct<<4) + (lane&15);
    Wpk2[i] = (_Float16)W2[(size_t)k*NHID + c];
  } else if (idx < 114688){
    int i = idx - 98304;
    int j=i&7, lane=(i>>3)&63, ct=(i>>9)&3, kc=i>>11;
    int k = kc*32 + ((lane>>4)<<3) + j, c = (ct<<4) + (lane&15);
    float v = (c < 32) ? Wp1[(size_t)k*32 + c] : Wp1[(size_t)(256+k)*32 + (c-32)];
    Wpkp[i] = (_Float16)v;
  } else if (idx < 117760){
    int i = idx - 114688;               // < 3072
    int j=i&7, lane=(i>>3)&63, mt=(i>>9)&1, layer=i>>10;
    int k = ((lane>>4)<<3) + j, c = mt*16 + (lane&15);
    const float* W = (layer==0) ? Wm1 : (layer==1) ? Wm2 : (Wp1 + 512*32);
    Apke[i] = (_Float16)W[k*32 + c];
  }
}
// per-node contiguous range allocation: one global atomic per wave
__global__ void k_alloc(const int* __restrict__ deg, int* __restrict__ total,
                        int* __restrict__ row_start, int* __restrict__ csr_src,
                        int* __restrict__ cursor, int N){
  const int i = blockIdx.x*256 + threadIdx.x;
  const int lane = threadIdx.x & 63;
  const int v = (i < N) ? deg[i] + 1 : 0;   // +1 self-loop
  int s = v;                                 // inclusive wave scan
#pragma unroll
  for (int off = 1; off < 64; off <<= 1){
    int x = __shfl_up(s, off);
    if (lane >= off) s += x;
  }
  int base = 0;
  if (lane == 63) base = atomicAdd(total, s);
  base = __shfl(base, 63);
  const int rs = base + s - v;               // exclusive within wave
  if (i < N){
    row_start[i] = rs;
    csr_src[rs] = i;        // self-loop first
    cursor[i] = rs + 1;
  }
}
__global__ void k_fill_edges(const int* __restrict__ ei, int* __restrict__ cursor,
                             int* __restrict__ csr_src, int E){
  int e = blockIdx.x*256 + threadIdx.x;
  if (e < E){
    int src = ei[e], dst = ei[E + e];
    int p = atomicAdd(&cursor[dst], 1);
    csr_src[p] = src;
  }
}

// ---------------- MFMA GEMM (X@W) + alpha; H/AS/AD written HEAD-MAJOR ----------------
// H: [8][N][32] fp16; AS/AD: [8][N] fp32. INF32=false input X is head-major [8][N][32] h16.
template<int K, bool INF32>
__global__ __launch_bounds__(256) void k_gemm_mfma(
    const void* __restrict__ xin, const _Float16* __restrict__ Wpk,
    const float* __restrict__ asrc, const float* __restrict__ adst,
    h16* __restrict__ H, float* __restrict__ AS, float* __restrict__ AD, int N)
{
  __shared__ __align__(16) _Float16 xs[32][K+8];   // +8 halves pad
  const int t = threadIdx.x;
  const int n0 = blockIdx.x * 32;
  constexpr int K8 = K/8;
  for (int i = t; i < 32*K8; i += 256){
    int r = i / K8, c8 = (i - r*K8)*8;
    if (INF32){
      _Float16 v[8];
      if (n0+r < N){
        const float4* gp = (const float4*)((const float*)xin + (size_t)(n0+r)*K + c8);
        float4 u0 = gp[0], u1 = gp[1];
        v[0]=(_Float16)u0.x; v[1]=(_Float16)u0.y; v[2]=(_Float16)u0.z; v[3]=(_Float16)u0.w;
        v[4]=(_Float16)u1.x; v[5]=(_Float16)u1.y; v[6]=(_Float16)u1.z; v[7]=(_Float16)u1.w;
      } else {
        for (int j=0;j<8;j++) v[j]=(_Float16)0.f;
      }
      *(f16x8*)&xs[r][c8] = *(f16x8*)v;
    } else {
      // head-major source: channel c8 -> head c8>>5, within c8&31
      uint4 u = make_uint4(0,0,0,0);
      if (n0+r < N)
        u = *(const uint4*)((const h16*)xin + ((size_t)(c8>>5)*N + (n0+r))*32 + (c8&31));
      *(uint4*)&xs[r][c8] = u;
    }
  }
  __syncthreads();

  const int wid = t >> 6, lane = t & 63;
  const int mcol = lane & 15, kq = lane >> 4;
  f32x4 acc[4][2];
#pragma unroll
  for (int ct = 0; ct < 4; ct++)
#pragma unroll
    for (int rt = 0; rt < 2; rt++) acc[ct][rt] = (f32x4){0.f,0.f,0.f,0.f};

  for (int kc = 0; kc < K/32; kc++){
    f16x8 a0 = *(const f16x8*)&xs[mcol     ][kc*32 + kq*8];
    f16x8 a1 = *(const f16x8*)&xs[16 + mcol][kc*32 + kq*8];
#pragma unroll
    for (int ct = 0; ct < 4; ct++){
      f16x8 b = *(const f16x8*)&Wpk[(((size_t)kc*16 + wid*4 + ct)*64 + lane)*8];
      acc[ct][0] = __builtin_amdgcn_mfma_f32_16x16x32_f16(a0, b, acc[ct][0], 0,0,0);
      acc[ct][1] = __builtin_amdgcn_mfma_f32_16x16x32_f16(a1, b, acc[ct][1], 0,0,0);
    }
  }

  float av[4], dv[4];
#pragma unroll
  for (int ct = 0; ct < 4; ct++){
    int c = wid*64 + ct*16 + mcol;
    av[ct] = asrc[c]; dv[ct] = adst[c];
  }
#pragma unroll
  for (int rt = 0; rt < 2; rt++){
#pragma unroll
    for (int r = 0; r < 4; r++){
      const int n = n0 + rt*16 + kq*4 + r;
      const bool ok = n < N;
      if (ok){
#pragma unroll
        for (int ct = 0; ct < 4; ct++){
          // col = wid*64+ct*16+mcol -> head = wid*2+(ct>>1), within = (ct&1)*16+mcol
          H[((size_t)(wid*2 + (ct>>1))*N + n)*32 + (ct&1)*16 + mcol] = f2h(acc[ct][rt][r]);
        }
      }
      float s1a = acc[0][rt][r]*av[0] + acc[1][rt][r]*av[1];
      float s2a = acc[0][rt][r]*dv[0] + acc[1][rt][r]*dv[1];
      float s1b = acc[2][rt][r]*av[2] + acc[3][rt][r]*av[3];
      float s2b = acc[2][rt][r]*dv[2] + acc[3][rt][r]*dv[3];
#pragma unroll
      for (int off = 1; off < 16; off <<= 1){
        s1a += __shfl_xor(s1a, off); s2a += __shfl_xor(s2a, off);
        s1b += __shfl_xor(s1b, off); s2b += __shfl_xor(s2b, off);
      }
      if (mcol == 0 && ok){
        AS[(size_t)(wid*2    )*N + n] = s1a;  AD[(size_t)(wid*2    )*N + n] = s2a;
        AS[(size_t)(wid*2 + 1)*N + n] = s1b;  AD[(size_t)(wid*2 + 1)*N + n] = s2b;
      }
    }
  }
}

// ------------- GAT aggregation: 4-lane group per (node, head), head-split + XCD swizzle ----
// head = blockIdx&7 (XCD-affine), 64 nodes/block, 16 nodes/wave, lane cl owns edge k+cl.
// R11: H prefetch deepened to TWO chunks ahead (issue-to-use ~360cy > L2 latency ~250cy;
// depth-1 under-covered by ~70cy -> per-iteration stall). Inner accumulate uses float2
// ext-vectors so -ffp-contract=fast emits v_pk_fma_f32 (8 fma -> 4 pk_fma per 16B slice;
// bit-identical to fmaf). deg from deg[] (+1 self-loop); row_start is range-alloc order.
static __device__ __forceinline__ void acc8(f32x2v* acc, uint4 u, float w){
  union { uint4 u; __half2 h[4]; } x; x.u = u;
#pragma unroll
  for (int i = 0; i < 4; i++){
    float2 f = __half22float2(x.h[i]);
    f32x2v fv; fv.x = f.x; fv.y = f.y;
    acc[i] = fv * w + acc[i];     // contracts to v_pk_fma_f32
  }
}

__global__ __launch_bounds__(256) void k_gat_agg(
    const int* __restrict__ row_start, const int* __restrict__ csr_src,
    const int* __restrict__ degv,
    const h16* __restrict__ H, const float* __restrict__ AS, const float* __restrict__ AD,
    const float* __restrict__ bias, h16* __restrict__ Xout, int N)
{
  const int head = blockIdx.x & 7;
  const int t = threadIdx.x;
  const int wv = t >> 6, lane = t & 63;
  const int g = lane >> 2, cl = lane & 3;
  const int n = (blockIdx.x >> 3)*64 + wv*16 + g;
  if (n >= N) return;                      // uniform per 4-lane group
  const int rs = row_start[n];
  const int deg = degv[n] + 1;             // >=1 (self-loop)
  const h16* __restrict__ Hh = H + (size_t)head*N*32;
  const float* __restrict__ ASh = AS + (size_t)head*N;
  const float adv = AD[(size_t)head*N + n];
  const int co = cl*8;

  f32x2v acc[4];
#pragma unroll
  for (int i = 0; i < 4; i++){ acc[i].x = 0.f; acc[i].y = 0.f; }
  float dsum = 0.f;

  // ---- prologue: ids for chunks 0..2, AS for 0..1, H for chunks 0 and 1 ----
  const bool m0 = cl < deg, m1p = 4+cl < deg, m2p = 8+cl < deg;
  int s0 = m0  ? csr_src[rs+cl]   : 0;
  int s1 = m1p ? csr_src[rs+4+cl] : 0;
  int s2 = m2p ? csr_src[rs+8+cl] : 0;
  float a1 = m1p ? ASh[s1] : 0.f;          // AS value chunk k+1
  float w0;                                // weight chunk k
  {
    const float a0 = m0 ? ASh[s0] : 0.f;
    const float v = a0 + adv;
    const float e = v > 0.f ? v : 0.2f*v;
    w0 = m0 ? __expf(e) : 0.f;
  }
  uint4 u0, u1, u2, u3;                    // H rows chunk k
  {
    const int r0=__shfl(s0,0,4), r1=__shfl(s0,1,4), r2=__shfl(s0,2,4), r3=__shfl(s0,3,4);
    u0 = *(const uint4*)(Hh + (size_t)r0*32 + co);
    u1 = *(const uint4*)(Hh + (size_t)r1*32 + co);
    u2 = *(const uint4*)(Hh + (size_t)r2*32 + co);
    u3 = *(const uint4*)(Hh + (size_t)r3*32 + co);
  }
  uint4 v0, v1, v2, v3;                    // H rows chunk k+1
  {
    const int r0=__shfl(s1,0,4), r1=__shfl(s1,1,4), r2=__shfl(s1,2,4), r3=__shfl(s1,3,4);
    v0 = *(const uint4*)(Hh + (size_t)r0*32 + co);
    v1 = *(const uint4*)(Hh + (size_t)r1*32 + co);
    v2 = *(const uint4*)(Hh + (size_t)r2*32 + co);
    v3 = *(const uint4*)(Hh + (size_t)r3*32 + co);
  }

  int k = 0;
  for (;;){
    // 1) csr for chunk k+3 (consumed as s2 two iters later)
    const bool m3 = (k+12+cl) < deg;
    const int s3 = m3 ? csr_src[rs+k+12+cl] : 0;
    // 2) AS-gather for chunk k+2 (s2 loaded 2 iters ago -> ready)
    const float a2 = ((k+8+cl) < deg) ? ASh[s2] : 0.f;
    // 3) H gathers for chunk k+2 (2 iterations ahead of consumption)
    const int r0=__shfl(s2,0,4), r1=__shfl(s2,1,4), r2=__shfl(s2,2,4), r3=__shfl(s2,3,4);
    const uint4 x0 = *(const uint4*)(Hh + (size_t)r0*32 + co);
    const uint4 x1 = *(const uint4*)(Hh + (size_t)r1*32 + co);
    const uint4 x2 = *(const uint4*)(Hh + (size_t)r2*32 + co);
    const uint4 x3 = *(const uint4*)(Hh + (size_t)r3*32 + co);
    // 4) weight for chunk k+1 (a1 issued last iter -> ready)
    const bool m1 = (k+4+cl) < deg;
    float w1;
    {
      const float v = a1 + adv;
      const float e = v > 0.f ? v : 0.2f*v;
      w1 = m1 ? __expf(e) : 0.f;
    }
    // 5) consume chunk k (H rows prefetched 2 iterations ago)
    dsum += w0;
    const float b0=__shfl(w0,0,4), b1=__shfl(w0,1,4), b2=__shfl(w0,2,4), b3=__shfl(w0,3,4);
    acc8(acc, u0, b0); acc8(acc, u1, b1);
    acc8(acc, u2, b2); acc8(acc, u3, b3);

    if (k + 4 >= deg) break;
    k += 4;
    u0 = v0; u1 = v1; u2 = v2; u3 = v3;
    v0 = x0; v1 = x1; v2 = x2; v3 = x3;
    s1 = s2; s2 = s3; a1 = a2; w0 = w1;
  }
  // denominator: sum the per-lane partials across the 4-lane group
  dsum += __shfl_xor(dsum, 1);
  dsum += __shfl_xor(dsum, 2);
  const float inv_d = 1.f / dsum;

  const float4 b0 = *(const float4*)(bias + head*32 + co);
  const float4 b1 = *(const float4*)(bias + head*32 + co + 4);
  uint4 o;
  o.x = pk2(fmaxf(fmaf(acc[0].x, inv_d, b0.x), 0.f),
            fmaxf(fmaf(acc[0].y, inv_d, b0.y), 0.f));
  o.y = pk2(fmaxf(fmaf(acc[1].x, inv_d, b0.z), 0.f),
            fmaxf(fmaf(acc[1].y, inv_d, b0.w), 0.f));
  o.z = pk2(fmaxf(fmaf(acc[2].x, inv_d, b1.x), 0.f),
            fmaxf(fmaf(acc[2].y, inv_d, b1.y), 0.f));
  o.w = pk2(fmaxf(fmaf(acc[3].x, inv_d, b1.z), 0.f),
            fmaxf(fmaf(acc[3].y, inv_d, b1.w), 0.f));
  *(uint4*)(Xout + ((size_t)head*N + n)*32 + co) = o;
}

// ------------- MFMA node projections: P[N][64] = X2(head-major) @ Wcat -------------
__global__ __launch_bounds__(256) void k_node_proj_mfma(
    const h16* __restrict__ X2, const _Float16* __restrict__ Wpk,
    h16* __restrict__ P, int N)
{
  __shared__ __align__(16) _Float16 xs[64][NHID+8];
  const int t = threadIdx.x;
  const int n0 = blockIdx.x * 64;
  for (int i = t; i < 64*32; i += 256){
    int r = i >> 5, c8 = (i & 31)*8;
    uint4 u = make_uint4(0,0,0,0);
    if (n0+r < N)
      u = *(const uint4*)(X2 + ((size_t)(c8>>5)*N + (n0+r))*32 + (c8&31));
    *(uint4*)&xs[r][c8] = u;
  }
  __syncthreads();

  const int wid = t >> 6, lane = t & 63;
  const int mcol = lane & 15, kq = lane >> 4;
  f32x4 acc[4];
#pragma unroll
  for (int rt = 0; rt < 4; rt++) acc[rt] = (f32x4){0.f,0.f,0.f,0.f};

  for (int kc = 0; kc < 8; kc++){
    f16x8 b = *(const f16x8*)&Wpk[(((size_t)kc*4 + wid)*64 + lane)*8];
#pragma unroll
    for (int rt = 0; rt < 4; rt++){
      f16x8 a = *(const f16x8*)&xs[rt*16 + mcol][kc*32 + kq*8];
      acc[rt] = __builtin_amdgcn_mfma_f32_16x16x32_f16(a, b, acc[rt], 0,0,0);
    }
  }

  const int c = wid*16 + mcol;
#pragma unroll
  for (int rt = 0; rt < 4; rt++){
#pragma unroll
    for (int r = 0; r < 4; r++){
      const int n = n0 + rt*16 + kq*4 + r;
      if (n < N) P[(size_t)n*64 + c] = f2h(acc[rt][r]);
    }
  }
}

// ------------- edge tail, all-register MFMA: zero LDS, zero barriers -------------
// R9: ea loads issued FIRST (addresses blockIdx-static) so the ~900cy HBM hop overlaps
// the ei->P L2 chain. Order: ea issue -> ei issue -> P-gather issue -> fence -> pk2(ea)
// -> MFMA chain -> tail(P).
__global__ __launch_bounds__(256) void k_edge_mfma(
    const int* __restrict__ ei, const float* __restrict__ ea,
    const _Float16* __restrict__ Apk,
    const float* __restrict__ bm1, const float* __restrict__ bm2,
    const float* __restrict__ bp1,
    const h16* __restrict__ P, const float* __restrict__ Wp2,
    const float* __restrict__ bp2,
    float* __restrict__ out, int E)
{
  union U8 { f16x8 v; unsigned u[4]; };
  union U2 { uint2 u; __half2 h[2]; };
  const int t = threadIdx.x;
  const int wid = t >> 6, lane = t & 63;
  const int mcol = lane & 15, kq = lane >> 4;
  const int e0w = blockIdx.x*256 + wid*64;

  // ---- phase -1: issue ALL ea loads (non-temporal HBM stream; addresses static) ----
  f32x4v eu0[4], eu1[4]; bool okv[4];
#pragma unroll
  for (int nt = 0; nt < 4; nt++){
    const int e = e0w + nt*16 + mcol;
    okv[nt] = e < E;
    const size_t eo = okv[nt] ? (size_t)e*32 + kq*8 : 0;
    const f32x4v* gp = (const f32x4v*)(ea + eo);
    eu0[nt] = __builtin_nontemporal_load(gp);
    eu1[nt] = __builtin_nontemporal_load(gp + 1);
  }

  // ---- phase 0: ei loads (coalesced, broadcast across kq) ----
  int rowv[4], colv[4];
#pragma unroll
  for (int nt = 0; nt < 4; nt++){
    const int e = e0w + nt*16 + mcol;
    rowv[nt] = okv[nt] ? ei[e]     : 0;
    colv[nt] = okv[nt] ? ei[E + e] : 0;
  }
  // ---- phase 1: issue ALL P gathers (16 x 8B per lane), consumed in the tail ----
  U2 pr[2][4], pc[2][4];
#pragma unroll
  for (int nt = 0; nt < 4; nt++){
#pragma unroll
    for (int mt = 0; mt < 2; mt++){
      pr[mt][nt].u = *(const uint2*)(P + (size_t)rowv[nt]*64      + mt*16 + kq*4);
      pc[mt][nt].u = *(const uint2*)(P + (size_t)colv[nt]*64 + 32 + mt*16 + kq*4);
    }
  }
  __builtin_amdgcn_sched_barrier(0);   // keep all load-issues above the compute chain

  float4 bv1[2], bv2[2], bv3[2], wv4[2];
#pragma unroll
  for (int mt = 0; mt < 2; mt++){
    bv1[mt] = *(const float4*)(bm1 + mt*16 + kq*4);
    bv2[mt] = *(const float4*)(bm2 + mt*16 + kq*4);
    bv3[mt] = *(const float4*)(bp1 + mt*16 + kq*4);
    wv4[mt] = *(const float4*)(Wp2 + mt*16 + kq*4);
  }
  const float bp2v = bp2[0];

  f32x4 acc[2][4];
  unsigned pkLo[2][4], pkHi[2][4];
  const int l1 = (kq & 1)*32 + mcol;
  const int l2 = l1 + 16;
  const int mt_hi = kq >> 1;

  // ---- layer 1: B from prefetched ea regs ----
#pragma unroll
  for (int nt = 0; nt < 4; nt++){
    U8 b;
    if (okv[nt]){
      b.u[0] = pk2(eu0[nt].x, eu0[nt].y); b.u[1] = pk2(eu0[nt].z, eu0[nt].w);
      b.u[2] = pk2(eu1[nt].x, eu1[nt].y); b.u[3] = pk2(eu1[nt].z, eu1[nt].w);
    } else {
      b.u[0]=b.u[1]=b.u[2]=b.u[3]=0u;
    }
#pragma unroll
    for (int mt = 0; mt < 2; mt++){
      f16x8 a = *(const f16x8*)&Apk[((0*2+mt)*64 + lane)*8];
      acc[mt][nt] = (f32x4){bv1[mt].x, bv1[mt].y, bv1[mt].z, bv1[mt].w};
      acc[mt][nt] = __builtin_amdgcn_mfma_f32_16x16x32_f16(a, b.v, acc[mt][nt], 0,0,0);
    }
  }

  // ---- transitions + layers 2,3 ----
#pragma unroll
  for (int layer = 1; layer < 3; layer++){
#pragma unroll
    for (int mt = 0; mt < 2; mt++)
#pragma unroll
      for (int nt = 0; nt < 4; nt++){
        float r0 = fmaxf(acc[mt][nt][0], 0.f), r1 = fmaxf(acc[mt][nt][1], 0.f);
        float r2 = fmaxf(acc[mt][nt][2], 0.f), r3 = fmaxf(acc[mt][nt][3], 0.f);
        pkLo[mt][nt] = pk2(r0, r1);
        pkHi[mt][nt] = pk2(r2, r3);
      }
#pragma unroll
    for (int nt = 0; nt < 4; nt++){
      unsigned a0 = (unsigned)__shfl((int)pkLo[0][nt], l1);
      unsigned a1 = (unsigned)__shfl((int)pkHi[0][nt], l1);
      unsigned a2 = (unsigned)__shfl((int)pkLo[0][nt], l2);
      unsigned a3 = (unsigned)__shfl((int)pkHi[0][nt], l2);
      unsigned c0 = (unsigned)__shfl((int)pkLo[1][nt], l1);
      unsigned c1 = (unsigned)__shfl((int)pkHi[1][nt], l1);
      unsigned c2 = (unsigned)__shfl((int)pkLo[1][nt], l2);
      unsigned c3 = (unsigned)__shfl((int)pkHi[1][nt], l2);
      U8 b;
      b.u[0] = mt_hi ? c0 : a0; b.u[1] = mt_hi ? c1 : a1;
      b.u[2] = mt_hi ? c2 : a2; b.u[3] = mt_hi ? c3 : a3;
      const float4 bv = (layer==1) ? bv2[0] : bv3[0];
      const float4 bw = (layer==1) ? bv2[1] : bv3[1];
      f16x8 A0 = *(const f16x8*)&Apk[((layer*2+0)*64 + lane)*8];
      f16x8 A1 = *(const f16x8*)&Apk[((layer*2+1)*64 + lane)*8];
      f32x4 n0 = (f32x4){bv.x, bv.y, bv.z, bv.w};
      f32x4 n1 = (f32x4){bw.x, bw.y, bw.z, bw.w};
      n0 = __builtin_amdgcn_mfma_f32_16x16x32_f16(A0, b.v, n0, 0,0,0);
      n1 = __builtin_amdgcn_mfma_f32_16x16x32_f16(A1, b.v, n1, 0,0,0);
      acc[0][nt] = n0;
      acc[1][nt] = n1;
    }
  }

  // ---- tail: p = sum_c relu(P1[row][c]+P2[col][c]+EC[e][c]) * Wp2[c] (P prefetched) ----
#pragma unroll
  for (int nt = 0; nt < 4; nt++){
    float p = 0.f;
#pragma unroll
    for (int mt = 0; mt < 2; mt++){
      __half2 x0 = pr[mt][nt].h[0], x1 = pr[mt][nt].h[1];
      __half2 y0 = pc[mt][nt].h[0], y1 = pc[mt][nt].h[1];
      float v0 = __half2float(x0.x) + __half2float(y0.x) + acc[mt][nt][0];
      float v1 = __half2float(x0.y) + __half2float(y0.y) + acc[mt][nt][1];
      float v2 = __half2float(x1.x) + __half2float(y1.x) + acc[mt][nt][2];
      float v3 = __half2float(x1.y) + __half2float(y1.y) + acc[mt][nt][3];
      v0 = fmaxf(v0,0.f); v1 = fmaxf(v1,0.f); v2 = fmaxf(v2,0.f); v3 = fmaxf(v3,0.f);
      p += v0*wv4[mt].x + v1*wv4[mt].y + v2*wv4[mt].z + v3*wv4[mt].w;
    }
    p += __shfl_xor(p, 16);
    p += __shfl_xor(p, 32);
    if (kq == 0 && okv[nt]) out[e0w + nt*16 + mcol] = p + bp2v;
  }
}

extern "C" void kernel_launch(void* const* d_in, const int* in_sizes, int n_in,
                              void* d_out, int out_size, void* d_ws, size_t ws_size,
                              hipStream_t stream)
{
  const float* x   = (const float*)d_in[0];
  const int*   ei  = (const int*)  d_in[1];
  const float* ea  = (const float*)d_in[2];
  const float* W1  = (const float*)d_in[3];
  const float* as1 = (const float*)d_in[4];
  const float* ad1 = (const float*)d_in[5];
  const float* b1  = (const float*)d_in[6];
  const float* W2  = (const float*)d_in[7];
  const float* as2 = (const float*)d_in[8];
  const float* ad2 = (const float*)d_in[9];
  const float* b2  = (const float*)d_in[10];
  const float* Wm1 = (const float*)d_in[11];
  const float* bm1 = (const float*)d_in[12];
  const float* Wm2 = (const float*)d_in[13];
  const float* bm2 = (const float*)d_in[14];
  const float* Wp1 = (const float*)d_in[15];
  const float* bp1 = (const float*)d_in[16];
  const float* Wp2 = (const float*)d_in[17];
  const float* bp2 = (const float*)d_in[18];

  const int N = in_sizes[0] / 128;    // 50000
  const int E = in_sizes[1] / 2;      // 400000

  char* p = (char*)d_ws;
  auto carve = [&](size_t bytes) -> void* {
    void* q = (void*)p; p += (bytes + 255) & ~size_t(255); return q;
  };
  h16* Hh   = (h16*)carve((size_t)N*NHID*2);      // 25.6 MB [8][N][32]
  h16* Xh   = (h16*)carve((size_t)N*NHID*2);      // 25.6 MB [8][N][32] (X1 then X2)
  float* AS = (float*)carve((size_t)N*HEADS*4);   // 1.6 MB [8][N]
  float* AD = (float*)carve((size_t)N*HEADS*4);   // 1.6 MB [8][N]
  h16* P    = (h16*)carve((size_t)N*64*2);        // 6.4 MB  [N][64] = [P1|P2]
  int* deg       = (int*)carve((size_t)(N+1)*4);  // deg[N] + total counter (one memset)
  int* total     = deg + N;
  int* cursor    = (int*)carve((size_t)N*4);
  int* row_start = (int*)carve((size_t)N*4);
  int* csr_src   = (int*)carve((size_t)(E+N)*4);
  _Float16* Wpk1 = (_Float16*)carve((size_t)128*NHID*2);  // 64 KB
  _Float16* Wpk2 = (_Float16*)carve((size_t)256*NHID*2);  // 128 KB
  _Float16* Wpkp = (_Float16*)carve((size_t)256*64*2);    // 32 KB
  _Float16* Apke = (_Float16*)carve((size_t)3072*2);      // 6 KB

  const int NB = (N + 255)/256;       // 196
  const int EB = (E + 255)/256;

  // CSR by dst (self-loop stored first per node); deg+total zero-init via one memset.
  (void)hipMemsetAsync(deg, 0, (size_t)(N+1)*4, stream);
  k_count_pack<<<EB + 460,256,0,stream>>>(ei, deg, E, EB,
                                          W1, W2, Wp1, Wm1, Wm2,
                                          Wpk1, Wpk2, Wpkp, Apke);
  k_alloc     <<<NB,256,0,stream>>>(deg, total, row_start, csr_src, cursor, N);
  k_fill_edges<<<EB,256,0,stream>>>(ei, cursor, csr_src, E);

  const int GB = (N + 31)/32;
  const int AB = 8 * ((N + 63)/64);   // head-split agg grid (head = blockIdx & 7)
  // GAT layer 1:  x(fp32) -> Hh -> Xh
  k_gemm_mfma<128,true ><<<GB,256,0,stream>>>(x,  Wpk1, as1, ad1, Hh, AS, AD, N);
  k_gat_agg<<<AB,256,0,stream>>>(row_start, csr_src, deg, Hh, AS, AD, b1, Xh, N);
  // GAT layer 2:  Xh -> Hh -> Xh
  k_gemm_mfma<256,false><<<GB,256,0,stream>>>(Xh, Wpk2, as2, ad2, Hh, AS, AD, N);
  k_gat_agg<<<AB,256,0,stream>>>(row_start, csr_src, deg, Hh, AS, AD, b2, Xh, N);

  // predictor decomposition
  k_node_proj_mfma<<<(N+63)/64,256,0,stream>>>(Xh, Wpkp, P, N);
  k_edge_mfma<<<(E+255)/256,256,0,stream>>>(ei, ea, Apke, bm1, bm2, bp1,
                                            P, Wp2, bp2, (float*)d_out, E);
}

// Round 12
// 334.747 us; speedup vs baseline: 1.0383x; 1.0383x over previous
//
#include <hip/hip_runtime.h>
#include <hip/hip_fp16.h>

typedef __half h16;
static __device__ __forceinline__ h16  f2h(float v){ return __float2half(v); }

typedef _Float16 f16x8 __attribute__((ext_vector_type(8)));
typedef float    f32x4 __attribute__((ext_vector_type(4)));
// clang ext-vector types for nontemporal builtins (HIP_vector_type is rejected)
typedef float    f32x4v __attribute__((ext_vector_type(4)));

// pack two floats -> h2 in a uint (RNE)
static __device__ __forceinline__ unsigned pk2(float a, float b){
  return ((unsigned)__half_as_ushort(__float2half(b)) << 16) |
          (unsigned)__half_as_ushort(__float2half(a));
}

#define HEADS 8
#define HID 32
#define NHID 256

// ---------------- CSR build (deg zeroed via memset; +1 self-loop added in scans) ----------------
// count_deg merged with weight packing (independent block ranges, saves one launch).
// Scan-chain CSR build (R9 form): matched-pair comparison vs the R10 atomic allocator
// showed the scan chain ~9us faster end-to-end (R9 336.7 vs R10 345.7).
__global__ void k_count_pack(const int* __restrict__ ei, int* __restrict__ deg, int E, int EB,
                             const float* __restrict__ W1, const float* __restrict__ W2,
                             const float* __restrict__ Wp1, const float* __restrict__ Wm1,
                             const float* __restrict__ Wm2,
                             _Float16* __restrict__ Wpk1, _Float16* __restrict__ Wpk2,
                             _Float16* __restrict__ Wpkp, _Float16* __restrict__ Apke){
  const int b = blockIdx.x;
  if (b < EB){
    int e = b*256 + threadIdx.x;
    if (e < E) atomicAdd(&deg[ei[E + e]], 1);   // dst = edge_index[1]
    return;
  }
  int idx = (b - EB)*256 + threadIdx.x;
  if (idx < 32768){
    int i = idx;
    int j=i&7, lane=(i>>3)&63, ct=(i>>9)&15, kc=i>>13;
    int k = kc*32 + ((lane>>4)<<3) + j, c = (ct<<4) + (lane&15);
    Wpk1[i] = (_Float16)W1[(size_t)k*NHID + c];
  } else if (idx < 98304){
    int i = idx - 32768;
    int j=i&7, lane=(i>>3)&63, ct=(i>>9)&15, kc=i>>13;
    int k = kc*32 + ((lane>>4)<<3) + j, c = (ct<<4) + (lane&15);
    Wpk2[i] = (_Float16)W2[(size_t)k*NHID + c];
  } else if (idx < 114688){
    int i = idx - 98304;
    int j=i&7, lane=(i>>3)&63, ct=(i>>9)&3, kc=i>>11;
    int k = kc*32 + ((lane>>4)<<3) + j, c = (ct<<4) + (lane&15);
    float v = (c < 32) ? Wp1[(size_t)k*32 + c] : Wp1[(size_t)(256+k)*32 + (c-32)];
    Wpkp[i] = (_Float16)v;
  } else if (idx < 117760){
    int i = idx - 114688;               // < 3072
    int j=i&7, lane=(i>>3)&63, mt=(i>>9)&1, layer=i>>10;
    int k = ((lane>>4)<<3) + j, c = mt*16 + (lane&15);
    const float* W = (layer==0) ? Wm1 : (layer==1) ? Wm2 : (Wp1 + 512*32);
    Apke[i] = (_Float16)W[k*32 + c];
  }
}
__global__ void k_scan_part(const int* __restrict__ deg, int* __restrict__ bsum, int N){
  __shared__ int s[256];
  int t = threadIdx.x, i = blockIdx.x*256 + t;
  s[t] = (i < N) ? deg[i] + 1 : 0;
  __syncthreads();
  for (int off = 128; off > 0; off >>= 1){
    if (t < off) s[t] += s[t+off];
    __syncthreads();
  }
  if (t == 0) bsum[blockIdx.x] = s[0];
}
__global__ void k_scan_top(const int* __restrict__ bsum, int* __restrict__ bpre, int nb){
  __shared__ int s[256];
  int t = threadIdx.x;
  int v = (t < nb) ? bsum[t] : 0;
  s[t] = v; __syncthreads();
  for (int off = 1; off < 256; off <<= 1){
    int x = (t >= off) ? s[t-off] : 0;
    __syncthreads();
    s[t] += x;
    __syncthreads();
  }
  if (t < nb) bpre[t] = s[t] - v;             // exclusive block prefix
}
// also fills self-loop entry + cursor
__global__ void k_scan_final(const int* __restrict__ deg, const int* __restrict__ bpre,
                             int* __restrict__ row_start, int* __restrict__ csr_src,
                             int* __restrict__ cursor, int N, int total){
  __shared__ int s[256];
  int t = threadIdx.x, i = blockIdx.x*256 + t;
  int v = (i < N) ? deg[i] + 1 : 0;
  s[t] = v; __syncthreads();
  for (int off = 1; off < 256; off <<= 1){
    int x = (t >= off) ? s[t-off] : 0;
    __syncthreads();
    s[t] += x;
    __syncthreads();
  }
  if (i < N){
    int p = bpre[blockIdx.x] + s[t] - v;
    row_start[i] = p;
    csr_src[p] = i;          // self-loop first
    cursor[i] = p + 1;
  }
  if (i == 0) row_start[N] = total;
}
__global__ void k_fill_edges(const int* __restrict__ ei, int* __restrict__ cursor,
                             int* __restrict__ csr_src, int E){
  int e = blockIdx.x*256 + threadIdx.x;
  if (e < E){
    int src = ei[e], dst = ei[E + e];
    int p = atomicAdd(&cursor[dst], 1);
    csr_src[p] = src;
  }
}

// ---------------- MFMA GEMM (X@W) + alpha; H/AS/AD written HEAD-MAJOR ----------------
// H: [8][N][32] fp16; AS/AD: [8][N] fp32. INF32=false input X is head-major [8][N][32] h16.
template<int K, bool INF32>
__global__ __launch_bounds__(256) void k_gemm_mfma(
    const void* __restrict__ xin, const _Float16* __restrict__ Wpk,
    const float* __restrict__ asrc, const float* __restrict__ adst,
    h16* __restrict__ H, float* __restrict__ AS, float* __restrict__ AD, int N)
{
  __shared__ __align__(16) _Float16 xs[32][K+8];   // +8 halves pad
  const int t = threadIdx.x;
  const int n0 = blockIdx.x * 32;
  constexpr int K8 = K/8;
  for (int i = t; i < 32*K8; i += 256){
    int r = i / K8, c8 = (i - r*K8)*8;
    if (INF32){
      _Float16 v[8];
      if (n0+r < N){
        const float4* gp = (const float4*)((const float*)xin + (size_t)(n0+r)*K + c8);
        float4 u0 = gp[0], u1 = gp[1];
        v[0]=(_Float16)u0.x; v[1]=(_Float16)u0.y; v[2]=(_Float16)u0.z; v[3]=(_Float16)u0.w;
        v[4]=(_Float16)u1.x; v[5]=(_Float16)u1.y; v[6]=(_Float16)u1.z; v[7]=(_Float16)u1.w;
      } else {
        for (int j=0;j<8;j++) v[j]=(_Float16)0.f;
      }
      *(f16x8*)&xs[r][c8] = *(f16x8*)v;
    } else {
      // head-major source: channel c8 -> head c8>>5, within c8&31
      uint4 u = make_uint4(0,0,0,0);
      if (n0+r < N)
        u = *(const uint4*)((const h16*)xin + ((size_t)(c8>>5)*N + (n0+r))*32 + (c8&31));
      *(uint4*)&xs[r][c8] = u;
    }
  }
  __syncthreads();

  const int wid = t >> 6, lane = t & 63;
  const int mcol = lane & 15, kq = lane >> 4;
  f32x4 acc[4][2];
#pragma unroll
  for (int ct = 0; ct < 4; ct++)
#pragma unroll
    for (int rt = 0; rt < 2; rt++) acc[ct][rt] = (f32x4){0.f,0.f,0.f,0.f};

  for (int kc = 0; kc < K/32; kc++){
    f16x8 a0 = *(const f16x8*)&xs[mcol     ][kc*32 + kq*8];
    f16x8 a1 = *(const f16x8*)&xs[16 + mcol][kc*32 + kq*8];
#pragma unroll
    for (int ct = 0; ct < 4; ct++){
      f16x8 b = *(const f16x8*)&Wpk[(((size_t)kc*16 + wid*4 + ct)*64 + lane)*8];
      acc[ct][0] = __builtin_amdgcn_mfma_f32_16x16x32_f16(a0, b, acc[ct][0], 0,0,0);
      acc[ct][1] = __builtin_amdgcn_mfma_f32_16x16x32_f16(a1, b, acc[ct][1], 0,0,0);
    }
  }

  float av[4], dv[4];
#pragma unroll
  for (int ct = 0; ct < 4; ct++){
    int c = wid*64 + ct*16 + mcol;
    av[ct] = asrc[c]; dv[ct] = adst[c];
  }
#pragma unroll
  for (int rt = 0; rt < 2; rt++){
#pragma unroll
    for (int r = 0; r < 4; r++){
      const int n = n0 + rt*16 + kq*4 + r;
      const bool ok = n < N;
      if (ok){
#pragma unroll
        for (int ct = 0; ct < 4; ct++){
          // col = wid*64+ct*16+mcol -> head = wid*2+(ct>>1), within = (ct&1)*16+mcol
          H[((size_t)(wid*2 + (ct>>1))*N + n)*32 + (ct&1)*16 + mcol] = f2h(acc[ct][rt][r]);
        }
      }
      float s1a = acc[0][rt][r]*av[0] + acc[1][rt][r]*av[1];
      float s2a = acc[0][rt][r]*dv[0] + acc[1][rt][r]*dv[1];
      float s1b = acc[2][rt][r]*av[2] + acc[3][rt][r]*av[3];
      float s2b = acc[2][rt][r]*dv[2] + acc[3][rt][r]*dv[3];
#pragma unroll
      for (int off = 1; off < 16; off <<= 1){
        s1a += __shfl_xor(s1a, off); s2a += __shfl_xor(s2a, off);
        s1b += __shfl_xor(s1b, off); s2b += __shfl_xor(s2b, off);
      }
      if (mcol == 0 && ok){
        AS[(size_t)(wid*2    )*N + n] = s1a;  AD[(size_t)(wid*2    )*N + n] = s2a;
        AS[(size_t)(wid*2 + 1)*N + n] = s1b;  AD[(size_t)(wid*2 + 1)*N + n] = s2b;
      }
    }
  }
}

// ------------- GAT aggregation: 4-lane group per (node, head), head-split + XCD swizzle ----
// head = blockIdx&7 (XCD-affine), 64 nodes/block, 16 nodes/wave, lane cl owns edge k+cl.
// R4 pipelined form (best measured ~40.5us): csr 3 chunks ahead, AS 2 ahead, exp/H 1 ahead.
// Measured equilibrium: TA ~12us floor, VALU ~17us, rest partially-exposed L2 latency.
// Failed levers (keep for the record): MLP co-schedule (VGPR cliff), degree-sort perm
// (Xout RMW +48MB), depth-2 prefetch + pk_fma (occupancy 54->47%, +3.4us).
static __device__ __forceinline__ void acc8(float* acc, uint4 u, float w){
  union { uint4 u; __half2 h[4]; } x; x.u = u;
#pragma unroll
  for (int i = 0; i < 4; i++){
    float2 f = __half22float2(x.h[i]);
    acc[2*i]   = fmaf(w, f.x, acc[2*i]);
    acc[2*i+1] = fmaf(w, f.y, acc[2*i+1]);
  }
}

__global__ __launch_bounds__(256) void k_gat_agg(
    const int* __restrict__ row_start, const int* __restrict__ csr_src,
    const h16* __restrict__ H, const float* __restrict__ AS, const float* __restrict__ AD,
    const float* __restrict__ bias, h16* __restrict__ Xout, int N)
{
  const int head = blockIdx.x & 7;
  const int t = threadIdx.x;
  const int wv = t >> 6, lane = t & 63;
  const int g = lane >> 2, cl = lane & 3;
  const int n = (blockIdx.x >> 3)*64 + wv*16 + g;
  if (n >= N) return;                      // uniform per 4-lane group
  const int rs = row_start[n];
  const int deg = row_start[n+1] - rs;     // >=1 (self-loop)
  const h16* __restrict__ Hh = H + (size_t)head*N*32;
  const float* __restrict__ ASh = AS + (size_t)head*N;
  const float adv = AD[(size_t)head*N + n];
  const int co = cl*8;

  float acc[8] = {0,0,0,0,0,0,0,0};
  float dsum = 0.f;

  // ---- prologue: fill the pipe for chunks 0..2 ----
  const bool m0 = cl < deg, m1p = 4+cl < deg, m2p = 8+cl < deg;
  int s1 = m1p ? csr_src[rs+4+cl] : 0;     // ids chunk k+1
  int s2 = m2p ? csr_src[rs+8+cl] : 0;     // ids chunk k+2
  int s0 = m0 ? csr_src[rs+cl]   : 0;      // ids chunk 0
  float a1 = m1p ? ASh[s1] : 0.f;          // AS value chunk k+1
  float w0;                                // weight chunk k
  {
    const float a0 = m0 ? ASh[s0] : 0.f;
    const float v = a0 + adv;
    const float e = v > 0.f ? v : 0.2f*v;
    w0 = m0 ? __expf(e) : 0.f;
  }
  uint4 u0, u1, u2, u3;                    // H rows chunk k
  {
    const int r0=__shfl(s0,0,4), r1=__shfl(s0,1,4), r2=__shfl(s0,2,4), r3=__shfl(s0,3,4);
    u0 = *(const uint4*)(Hh + (size_t)r0*32 + co);
    u1 = *(const uint4*)(Hh + (size_t)r1*32 + co);
    u2 = *(const uint4*)(Hh + (size_t)r2*32 + co);
    u3 = *(const uint4*)(Hh + (size_t)r3*32 + co);
  }

  int k = 0;
  for (;;){
    // 1) csr for chunk k+3 (issue; consumed as s2 two iters later)
    const bool m3 = (k+12+cl) < deg;
    const int s3 = m3 ? csr_src[rs+k+12+cl] : 0;
    // 2) AS-gather for chunk k+2 (s2 was loaded last iter -> ready)
    const bool m2 = (k+8+cl) < deg;
    const float a2 = m2 ? ASh[s2] : 0.f;
    // 3) H gathers for chunk k+1 (s1 ready)
    const int r0=__shfl(s1,0,4), r1=__shfl(s1,1,4), r2=__shfl(s1,2,4), r3=__shfl(s1,3,4);
    const uint4 v0 = *(const uint4*)(Hh + (size_t)r0*32 + co);
    const uint4 v1 = *(const uint4*)(Hh + (size_t)r1*32 + co);
    const uint4 v2 = *(const uint4*)(Hh + (size_t)r2*32 + co);
    const uint4 v3 = *(const uint4*)(Hh + (size_t)r3*32 + co);
    // 4) weight for chunk k+1 (a1 issued last iter -> ready)
    const bool m1 = (k+4+cl) < deg;
    float w1;
    {
      const float v = a1 + adv;
      const float e = v > 0.f ? v : 0.2f*v;
      w1 = m1 ? __expf(e) : 0.f;
    }
    // 5) consume chunk k
    dsum += w0;
    const float b0=__shfl(w0,0,4), b1=__shfl(w0,1,4), b2=__shfl(w0,2,4), b3=__shfl(w0,3,4);
    acc8(acc, u0, b0); acc8(acc, u1, b1);
    acc8(acc, u2, b2); acc8(acc, u3, b3);

    if (k + 4 >= deg) break;
    k += 4;
    s1 = s2; s2 = s3; a1 = a2; w0 = w1;
    u0 = v0; u1 = v1; u2 = v2; u3 = v3;
  }
  // denominator: sum the per-lane partials across the 4-lane group
  dsum += __shfl_xor(dsum, 1);
  dsum += __shfl_xor(dsum, 2);
  const float inv_d = 1.f / dsum;

  const float4 b0 = *(const float4*)(bias + head*32 + co);
  const float4 b1 = *(const float4*)(bias + head*32 + co + 4);
  uint4 o;
  o.x = pk2(fmaxf(fmaf(acc[0], inv_d, b0.x), 0.f),
            fmaxf(fmaf(acc[1], inv_d, b0.y), 0.f));
  o.y = pk2(fmaxf(fmaf(acc[2], inv_d, b0.z), 0.f),
            fmaxf(fmaf(acc[3], inv_d, b0.w), 0.f));
  o.z = pk2(fmaxf(fmaf(acc[4], inv_d, b1.x), 0.f),
            fmaxf(fmaf(acc[5], inv_d, b1.y), 0.f));
  o.w = pk2(fmaxf(fmaf(acc[6], inv_d, b1.z), 0.f),
            fmaxf(fmaf(acc[7], inv_d, b1.w), 0.f));
  *(uint4*)(Xout + ((size_t)head*N + n)*32 + co) = o;
}

// ------------- MFMA node projections: P[N][64] = X2(head-major) @ Wcat -------------
__global__ __launch_bounds__(256) void k_node_proj_mfma(
    const h16* __restrict__ X2, const _Float16* __restrict__ Wpk,
    h16* __restrict__ P, int N)
{
  __shared__ __align__(16) _Float16 xs[64][NHID+8];
  const int t = threadIdx.x;
  const int n0 = blockIdx.x * 64;
  for (int i = t; i < 64*32; i += 256){
    int r = i >> 5, c8 = (i & 31)*8;
    uint4 u = make_uint4(0,0,0,0);
    if (n0+r < N)
      u = *(const uint4*)(X2 + ((size_t)(c8>>5)*N + (n0+r))*32 + (c8&31));
    *(uint4*)&xs[r][c8] = u;
  }
  __syncthreads();

  const int wid = t >> 6, lane = t & 63;
  const int mcol = lane & 15, kq = lane >> 4;
  f32x4 acc[4];
#pragma unroll
  for (int rt = 0; rt < 4; rt++) acc[rt] = (f32x4){0.f,0.f,0.f,0.f};

  for (int kc = 0; kc < 8; kc++){
    f16x8 b = *(const f16x8*)&Wpk[(((size_t)kc*4 + wid)*64 + lane)*8];
#pragma unroll
    for (int rt = 0; rt < 4; rt++){
      f16x8 a = *(const f16x8*)&xs[rt*16 + mcol][kc*32 + kq*8];
      acc[rt] = __builtin_amdgcn_mfma_f32_16x16x32_f16(a, b, acc[rt], 0,0,0);
    }
  }

  const int c = wid*16 + mcol;
#pragma unroll
  for (int rt = 0; rt < 4; rt++){
#pragma unroll
    for (int r = 0; r < 4; r++){
      const int n = n0 + rt*16 + kq*4 + r;
      if (n < N) P[(size_t)n*64 + c] = f2h(acc[rt][r]);
    }
  }
}

// ------------- edge tail, all-register MFMA: zero LDS, zero barriers -------------
// R9: ea loads issued FIRST (addresses blockIdx-static) so the ~900cy HBM hop overlaps
// the ei->P L2 chain. Order: ea issue -> ei issue -> P-gather issue -> fence -> pk2(ea)
// -> MFMA chain -> tail(P).
__global__ __launch_bounds__(256) void k_edge_mfma(
    const int* __restrict__ ei, const float* __restrict__ ea,
    const _Float16* __restrict__ Apk,
    const float* __restrict__ bm1, const float* __restrict__ bm2,
    const float* __restrict__ bp1,
    const h16* __restrict__ P, const float* __restrict__ Wp2,
    const float* __restrict__ bp2,
    float* __restrict__ out, int E)
{
  union U8 { f16x8 v; unsigned u[4]; };
  union U2 { uint2 u; __half2 h[2]; };
  const int t = threadIdx.x;
  const int wid = t >> 6, lane = t & 63;
  const int mcol = lane & 15, kq = lane >> 4;
  const int e0w = blockIdx.x*256 + wid*64;

  // ---- phase -1: issue ALL ea loads (non-temporal HBM stream; addresses static) ----
  f32x4v eu0[4], eu1[4]; bool okv[4];
#pragma unroll
  for (int nt = 0; nt < 4; nt++){
    const int e = e0w + nt*16 + mcol;
    okv[nt] = e < E;
    const size_t eo = okv[nt] ? (size_t)e*32 + kq*8 : 0;
    const f32x4v* gp = (const f32x4v*)(ea + eo);
    eu0[nt] = __builtin_nontemporal_load(gp);
    eu1[nt] = __builtin_nontemporal_load(gp + 1);
  }

  // ---- phase 0: ei loads (coalesced, broadcast across kq) ----
  int rowv[4], colv[4];
#pragma unroll
  for (int nt = 0; nt < 4; nt++){
    const int e = e0w + nt*16 + mcol;
    rowv[nt] = okv[nt] ? ei[e]     : 0;
    colv[nt] = okv[nt] ? ei[E + e] : 0;
  }
  // ---- phase 1: issue ALL P gathers (16 x 8B per lane), consumed in the tail ----
  U2 pr[2][4], pc[2][4];
#pragma unroll
  for (int nt = 0; nt < 4; nt++){
#pragma unroll
    for (int mt = 0; mt < 2; mt++){
      pr[mt][nt].u = *(const uint2*)(P + (size_t)rowv[nt]*64      + mt*16 + kq*4);
      pc[mt][nt].u = *(const uint2*)(P + (size_t)colv[nt]*64 + 32 + mt*16 + kq*4);
    }
  }
  __builtin_amdgcn_sched_barrier(0);   // keep all load-issues above the compute chain

  float4 bv1[2], bv2[2], bv3[2], wv4[2];
#pragma unroll
  for (int mt = 0; mt < 2; mt++){
    bv1[mt] = *(const float4*)(bm1 + mt*16 + kq*4);
    bv2[mt] = *(const float4*)(bm2 + mt*16 + kq*4);
    bv3[mt] = *(const float4*)(bp1 + mt*16 + kq*4);
    wv4[mt] = *(const float4*)(Wp2 + mt*16 + kq*4);
  }
  const float bp2v = bp2[0];

  f32x4 acc[2][4];
  unsigned pkLo[2][4], pkHi[2][4];
  const int l1 = (kq & 1)*32 + mcol;
  const int l2 = l1 + 16;
  const int mt_hi = kq >> 1;

  // ---- layer 1: B from prefetched ea regs ----
#pragma unroll
  for (int nt = 0; nt < 4; nt++){
    U8 b;
    if (okv[nt]){
      b.u[0] = pk2(eu0[nt].x, eu0[nt].y); b.u[1] = pk2(eu0[nt].z, eu0[nt].w);
      b.u[2] = pk2(eu1[nt].x, eu1[nt].y); b.u[3] = pk2(eu1[nt].z, eu1[nt].w);
    } else {
      b.u[0]=b.u[1]=b.u[2]=b.u[3]=0u;
    }
#pragma unroll
    for (int mt = 0; mt < 2; mt++){
      f16x8 a = *(const f16x8*)&Apk[((0*2+mt)*64 + lane)*8];
      acc[mt][nt] = (f32x4){bv1[mt].x, bv1[mt].y, bv1[mt].z, bv1[mt].w};
      acc[mt][nt] = __builtin_amdgcn_mfma_f32_16x16x32_f16(a, b.v, acc[mt][nt], 0,0,0);
    }
  }

  // ---- transitions + layers 2,3 ----
#pragma unroll
  for (int layer = 1; layer < 3; layer++){
#pragma unroll
    for (int mt = 0; mt < 2; mt++)
#pragma unroll
      for (int nt = 0; nt < 4; nt++){
        float r0 = fmaxf(acc[mt][nt][0], 0.f), r1 = fmaxf(acc[mt][nt][1], 0.f);
        float r2 = fmaxf(acc[mt][nt][2], 0.f), r3 = fmaxf(acc[mt][nt][3], 0.f);
        pkLo[mt][nt] = pk2(r0, r1);
        pkHi[mt][nt] = pk2(r2, r3);
      }
#pragma unroll
    for (int nt = 0; nt < 4; nt++){
      unsigned a0 = (unsigned)__shfl((int)pkLo[0][nt], l1);
      unsigned a1 = (unsigned)__shfl((int)pkHi[0][nt], l1);
      unsigned a2 = (unsigned)__shfl((int)pkLo[0][nt], l2);
      unsigned a3 = (unsigned)__shfl((int)pkHi[0][nt], l2);
      unsigned c0 = (unsigned)__shfl((int)pkLo[1][nt], l1);
      unsigned c1 = (unsigned)__shfl((int)pkHi[1][nt], l1);
      unsigned c2 = (unsigned)__shfl((int)pkLo[1][nt], l2);
      unsigned c3 = (unsigned)__shfl((int)pkHi[1][nt], l2);
      U8 b;
      b.u[0] = mt_hi ? c0 : a0; b.u[1] = mt_hi ? c1 : a1;
      b.u[2] = mt_hi ? c2 : a2; b.u[3] = mt_hi ? c3 : a3;
      const float4 bv = (layer==1) ? bv2[0] : bv3[0];
      const float4 bw = (layer==1) ? bv2[1] : bv3[1];
      f16x8 A0 = *(const f16x8*)&Apk[((layer*2+0)*64 + lane)*8];
      f16x8 A1 = *(const f16x8*)&Apk[((layer*2+1)*64 + lane)*8];
      f32x4 n0 = (f32x4){bv.x, bv.y, bv.z, bv.w};
      f32x4 n1 = (f32x4){bw.x, bw.y, bw.z, bw.w};
      n0 = __builtin_amdgcn_mfma_f32_16x16x32_f16(A0, b.v, n0, 0,0,0);
      n1 = __builtin_amdgcn_mfma_f32_16x16x32_f16(A1, b.v, n1, 0,0,0);
      acc[0][nt] = n0;
      acc[1][nt] = n1;
    }
  }

  // ---- tail: p = sum_c relu(P1[row][c]+P2[col][c]+EC[e][c]) * Wp2[c] (P prefetched) ----
#pragma unroll
  for (int nt = 0; nt < 4; nt++){
    float p = 0.f;
#pragma unroll
    for (int mt = 0; mt < 2; mt++){
      __half2 x0 = pr[mt][nt].h[0], x1 = pr[mt][nt].h[1];
      __half2 y0 = pc[mt][nt].h[0], y1 = pc[mt][nt].h[1];
      float v0 = __half2float(x0.x) + __half2float(y0.x) + acc[mt][nt][0];
      float v1 = __half2float(x0.y) + __half2float(y0.y) + acc[mt][nt][1];
      float v2 = __half2float(x1.x) + __half2float(y1.x) + acc[mt][nt][2];
      float v3 = __half2float(x1.y) + __half2float(y1.y) + acc[mt][nt][3];
      v0 = fmaxf(v0,0.f); v1 = fmaxf(v1,0.f); v2 = fmaxf(v2,0.f); v3 = fmaxf(v3,0.f);
      p += v0*wv4[mt].x + v1*wv4[mt].y + v2*wv4[mt].z + v3*wv4[mt].w;
    }
    p += __shfl_xor(p, 16);
    p += __shfl_xor(p, 32);
    if (kq == 0 && okv[nt]) out[e0w + nt*16 + mcol] = p + bp2v;
  }
}

extern "C" void kernel_launch(void* const* d_in, const int* in_sizes, int n_in,
                              void* d_out, int out_size, void* d_ws, size_t ws_size,
                              hipStream_t stream)
{
  const float* x   = (const float*)d_in[0];
  const int*   ei  = (const int*)  d_in[1];
  const float* ea  = (const float*)d_in[2];
  const float* W1  = (const float*)d_in[3];
  const float* as1 = (const float*)d_in[4];
  const float* ad1 = (const float*)d_in[5];
  const float* b1  = (const float*)d_in[6];
  const float* W2  = (const float*)d_in[7];
  const float* as2 = (const float*)d_in[8];
  const float* ad2 = (const float*)d_in[9];
  const float* b2  = (const float*)d_in[10];
  const float* Wm1 = (const float*)d_in[11];
  const float* bm1 = (const float*)d_in[12];
  const float* Wm2 = (const float*)d_in[13];
  const float* bm2 = (const float*)d_in[14];
  const float* Wp1 = (const float*)d_in[15];
  const float* bp1 = (const float*)d_in[16];
  const float* Wp2 = (const float*)d_in[17];
  const float* bp2 = (const float*)d_in[18];

  const int N = in_sizes[0] / 128;    // 50000
  const int E = in_sizes[1] / 2;      // 400000

  char* p = (char*)d_ws;
  auto carve = [&](size_t bytes) -> void* {
    void* q = (void*)p; p += (bytes + 255) & ~size_t(255); return q;
  };
  h16* Hh   = (h16*)carve((size_t)N*NHID*2);      // 25.6 MB [8][N][32]
  h16* Xh   = (h16*)carve((size_t)N*NHID*2);      // 25.6 MB [8][N][32] (X1 then X2)
  float* AS = (float*)carve((size_t)N*HEADS*4);   // 1.6 MB [8][N]
  float* AD = (float*)carve((size_t)N*HEADS*4);   // 1.6 MB [8][N]
  h16* P    = (h16*)carve((size_t)N*64*2);        // 6.4 MB  [N][64] = [P1|P2]
  int* deg       = (int*)carve((size_t)N*4);
  int* cursor    = (int*)carve((size_t)N*4);
  int* row_start = (int*)carve((size_t)(N+1)*4);
  int* csr_src   = (int*)carve((size_t)(E+N)*4);
  int* bsum      = (int*)carve(1024);
  int* bpre      = (int*)carve(1024);
  _Float16* Wpk1 = (_Float16*)carve((size_t)128*NHID*2);  // 64 KB
  _Float16* Wpk2 = (_Float16*)carve((size_t)256*NHID*2);  // 128 KB
  _Float16* Wpkp = (_Float16*)carve((size_t)256*64*2);    // 32 KB
  _Float16* Apke = (_Float16*)carve((size_t)3072*2);      // 6 KB

  const int NB = (N + 255)/256;       // 196 (<=256 required by scan_top)
  const int EB = (E + 255)/256;

  // CSR by dst (self-loop stored first per node); deg zero-init via memset.
  (void)hipMemsetAsync(deg, 0, (size_t)N*4, stream);
  k_count_pack<<<EB + 460,256,0,stream>>>(ei, deg, E, EB,
                                          W1, W2, Wp1, Wm1, Wm2,
                                          Wpk1, Wpk2, Wpkp, Apke);
  k_scan_part <<<NB,256,0,stream>>>(deg, bsum, N);
  k_scan_top  <<<1 ,256,0,stream>>>(bsum, bpre, NB);
  k_scan_final<<<NB,256,0,stream>>>(deg, bpre, row_start, csr_src, cursor, N, E + N);
  k_fill_edges<<<EB,256,0,stream>>>(ei, cursor, csr_src, E);

  const int GB = (N + 31)/32;
  const int AB = 8 * ((N + 63)/64);   // head-split agg grid (head = blockIdx & 7)
  // GAT layer 1:  x(fp32) -> Hh -> Xh
  k_gemm_mfma<128,true ><<<GB,256,0,stream>>>(x,  Wpk1, as1, ad1, Hh, AS, AD, N);
  k_gat_agg<<<AB,256,0,stream>>>(row_start, csr_src, Hh, AS, AD, b1, Xh, N);
  // GAT layer 2:  Xh -> Hh -> Xh
  k_gemm_mfma<256,false><<<GB,256,0,stream>>>(Xh, Wpk2, as2, ad2, Hh, AS, AD, N);
  k_gat_agg<<<AB,256,0,stream>>>(row_start, csr_src, Hh, AS, AD, b2, Xh, N);

  // predictor decomposition
  k_node_proj_mfma<<<(N+63)/64,256,0,stream>>>(Xh, Wpkp, P, N);
  k_edge_mfma<<<(E+255)/256,256,0,stream>>>(ei, ea, Apke, bm1, bm2, bp1,
                                            P, Wp2, bp2, (float*)d_out, E);
}